// Round 1
// baseline (439.765 us; speedup 1.0000x reference)
//
#include <hip/hip_runtime.h>
#include <hip/hip_bf16.h>

// Problem constants (from reference)
#define NE 8            // experts
#define NH 1024         // hidden
#define NF 2048         // ffn
#define NT 4096         // tokens = B*S
#define CAP 640         // ceil(1.25 * 4096 / 8)

typedef __bf16 bf16x8 __attribute__((ext_vector_type(8)));
typedef float f32x4 __attribute__((ext_vector_type(4)));

__device__ __forceinline__ ushort f2bf(float f) {
    union { float f; unsigned u; } v; v.f = f;
    unsigned r = (v.u + 0x7FFFu + ((v.u >> 16) & 1u)) >> 16;
    return (ushort)r;
}

// ---------------------------------------------------------------------------
// K1: per-token LayerNorm (fp32) + router logits + softmax + top-2
// grid = NT blocks, 256 threads; thread t handles h = tid*4 .. tid*4+3
// ---------------------------------------------------------------------------
__global__ __launch_bounds__(256) void k_ln_router(
    const float* __restrict__ x, const float* __restrict__ rw,
    const float* __restrict__ gamma, const float* __restrict__ beta,
    ushort* __restrict__ tok_bf, int* __restrict__ idx, float* __restrict__ wts)
{
    int t = blockIdx.x, tid = threadIdx.x;
    int lane = tid & 63, wid = tid >> 6;
    const float* xp = x + (size_t)t * NH;

    float4 v = *(const float4*)(xp + tid * 4);
    float xs[4] = {v.x, v.y, v.z, v.w};
    float s = xs[0] + xs[1] + xs[2] + xs[3];
    float q = xs[0]*xs[0] + xs[1]*xs[1] + xs[2]*xs[2] + xs[3]*xs[3];

    __shared__ float rs[4], rq[4], rl[4][8];
    #pragma unroll
    for (int o = 32; o; o >>= 1) { s += __shfl_xor(s, o); q += __shfl_xor(q, o); }
    if (lane == 0) { rs[wid] = s; rq[wid] = q; }
    __syncthreads();
    float S = rs[0] + rs[1] + rs[2] + rs[3];
    float Q = rq[0] + rq[1] + rq[2] + rq[3];
    float mean = S * (1.0f / NH);
    float var  = Q * (1.0f / NH) - mean * mean;
    float rstd = 1.0f / sqrtf(var + 1e-5f);

    float le[8] = {0,0,0,0,0,0,0,0};
    ushort tb[4];
    #pragma unroll
    for (int j = 0; j < 4; ++j) {
        int h = tid * 4 + j;
        float nh = (xs[j] - mean) * rstd * gamma[h] + beta[h];
        tb[j] = f2bf(nh);
        float4 r0 = *(const float4*)(rw + h * 8);
        float4 r1 = *(const float4*)(rw + h * 8 + 4);
        le[0] += nh * r0.x; le[1] += nh * r0.y; le[2] += nh * r0.z; le[3] += nh * r0.w;
        le[4] += nh * r1.x; le[5] += nh * r1.y; le[6] += nh * r1.z; le[7] += nh * r1.w;
    }
    union { ushort s2[4]; uint2 u2; } pk;
    pk.s2[0]=tb[0]; pk.s2[1]=tb[1]; pk.s2[2]=tb[2]; pk.s2[3]=tb[3];
    *(uint2*)(tok_bf + (size_t)t * NH + tid * 4) = pk.u2;

    #pragma unroll
    for (int o = 32; o; o >>= 1)
        #pragma unroll
        for (int e = 0; e < 8; ++e) le[e] += __shfl_xor(le[e], o);
    if (lane == 0)
        #pragma unroll
        for (int e = 0; e < 8; ++e) rl[wid][e] = le[e];
    __syncthreads();

    if (tid == 0) {
        float l[8];
        #pragma unroll
        for (int e = 0; e < 8; ++e) l[e] = rl[0][e] + rl[1][e] + rl[2][e] + rl[3][e];
        float mx = l[0];
        #pragma unroll
        for (int e = 1; e < 8; ++e) mx = fmaxf(mx, l[e]);
        float p[8], den = 0.f;
        #pragma unroll
        for (int e = 0; e < 8; ++e) { p[e] = expf(l[e] - mx); den += p[e]; }
        float rden = 1.0f / den;
        #pragma unroll
        for (int e = 0; e < 8; ++e) p[e] *= rden;
        // top-2, ties -> lowest index (matches jax.lax.top_k stability)
        int i0 = 0; float b0 = p[0];
        #pragma unroll
        for (int e = 1; e < 8; ++e) if (p[e] > b0) { b0 = p[e]; i0 = e; }
        int i1 = (i0 == 0) ? 1 : 0; float b1 = p[i1];
        #pragma unroll
        for (int e = 0; e < 8; ++e) if (e != i0 && p[e] > b1) { b1 = p[e]; i1 = e; }
        float sw = 1.0f / (b0 + b1);
        idx[2*t] = i0; idx[2*t+1] = i1;
        wts[2*t] = b0 * sw; wts[2*t+1] = b1 * sw;
    }
}

// ---------------------------------------------------------------------------
// K2: per-expert ordered compaction (stable by token index, capacity CAP)
// grid = NE blocks, 1024 threads
// ---------------------------------------------------------------------------
__global__ __launch_bounds__(1024) void k_build_sel(
    const int* __restrict__ idx, int* __restrict__ sel)
{
    int e = blockIdx.x, tid = threadIdx.x;
    int lane = tid & 63, wid = tid >> 6;
    __shared__ int wsum[16], wpre[16], sbase;
    if (tid < CAP) sel[e * CAP + tid] = -1;
    if (tid == 0) sbase = 0;
    __syncthreads();

    for (int ch = 0; ch < NT / 1024; ++ch) {
        int t = ch * 1024 + tid;
        int m = (idx[2*t] == e || idx[2*t+1] == e) ? 1 : 0;
        int v = m;
        #pragma unroll
        for (int d = 1; d < 64; d <<= 1) {
            int u = __shfl_up(v, d);
            if (lane >= d) v += u;
        }
        if (lane == 63) wsum[wid] = v;
        __syncthreads();
        if (tid < 16) {
            int ws = wsum[tid], wv = ws;
            #pragma unroll
            for (int d = 1; d < 16; d <<= 1) {
                int u = __shfl_up(wv, d);
                if (tid >= d) wv += u;
            }
            wpre[tid] = wv - ws;
        }
        __syncthreads();
        int base0 = sbase;
        int slot = base0 + wpre[wid] + v - m;   // exclusive prefix
        if (m && slot < CAP) sel[e * CAP + slot] = t;
        __syncthreads();
        if (tid == 0) sbase = base0 + wpre[15] + wsum[15];
        __syncthreads();
    }
}

// ---------------------------------------------------------------------------
// K3: gather tokens into per-expert slot rows (zeros for invalid slots)
// grid = NE*CAP blocks, 256 threads (4 bf16 each)
// ---------------------------------------------------------------------------
__global__ __launch_bounds__(256) void k_gather(
    const int* __restrict__ sel, const ushort* __restrict__ tok,
    ushort* __restrict__ xin)
{
    int sIdx = blockIdx.x;
    int tokid = sel[sIdx];
    uint2 v = make_uint2(0u, 0u);
    if (tokid >= 0)
        v = *(const uint2*)(tok + (size_t)tokid * NH + threadIdx.x * 4);
    *(uint2*)(xin + (size_t)sIdx * NH + threadIdx.x * 4) = v;
}

// ---------------------------------------------------------------------------
// B-tile staging helper: loads a 32 x BN fp32 tile column-wise (coalesced
// dword across lanes), converts to bf16, writes LDS transposed [BN][32+pad]
// ---------------------------------------------------------------------------
#define BPAD 40   // 32 + 8 pad elements -> 80B row stride, 16B aligned

__device__ __forceinline__ void stage_b_16(
    const float* __restrict__ Bp, ushort* __restrict__ Bl,
    int k0, int ldb, int bn, int bkh)
{
    // 16 k-values for column bn
    union { ushort sh[8]; uint4 v; } p0, p1;
    #pragma unroll
    for (int j = 0; j < 8; ++j) p0.sh[j] = f2bf(Bp[(k0 + bkh + j) * ldb + bn]);
    #pragma unroll
    for (int j = 0; j < 8; ++j) p1.sh[j] = f2bf(Bp[(k0 + bkh + 8 + j) * ldb + bn]);
    *(uint4*)&Bl[bn * BPAD + bkh] = p0.v;
    *(uint4*)&Bl[bn * BPAD + bkh + 8] = p1.v;
}

// ---------------------------------------------------------------------------
// GEMM1: hb[e] = silu(xin[e] @ wg[e]) * (xin[e] @ wu[e])   (M=CAP,N=NF,K=NH)
// tile 128x128x32, 256 threads (4 waves 2x2), bf16 MFMA 16x16x32
// ---------------------------------------------------------------------------
__global__ __launch_bounds__(256) void k_gemm1(
    const ushort* __restrict__ xin, const float* __restrict__ wg,
    const float* __restrict__ wu, ushort* __restrict__ hb)
{
    int e = blockIdx.z, mb = blockIdx.y, nb = blockIdx.x;
    const ushort* A  = xin + (size_t)e * CAP * NH + (size_t)mb * 128 * NH;
    const float*  Bg = wg  + (size_t)e * NH * NF + nb * 128;
    const float*  Bu = wu  + (size_t)e * NH * NF + nb * 128;
    ushort* out = hb + (size_t)e * CAP * NF + (size_t)mb * 128 * NF + nb * 128;

    __shared__ __align__(16) ushort Al[128 * BPAD];
    __shared__ __align__(16) ushort Bgl[128 * BPAD];
    __shared__ __align__(16) ushort Bul[128 * BPAD];

    int tid = threadIdx.x, lane = tid & 63, wid = tid >> 6;
    int wm = wid >> 1, wn = wid & 1;
    int lr = lane & 15, lq = lane >> 4;
    int bn  = wid * 32 + (lane & 31);       // column this thread stages
    int bkh = (lane >> 5) * 16;             // k-half

    f32x4 accg[4][4] = {}; f32x4 accu[4][4] = {};

    for (int k0 = 0; k0 < NH; k0 += 32) {
        // A: 128x32 bf16, 2 x 16B per thread
        #pragma unroll
        for (int i = 0; i < 2; ++i) {
            int L = tid + i * 256;
            int row = L >> 2, cg = (L & 3) * 8;
            uint4 av = *(const uint4*)(A + (size_t)row * NH + k0 + cg);
            *(uint4*)&Al[row * BPAD + cg] = av;
        }
        stage_b_16(Bg, Bgl, k0, NF, bn, bkh);
        stage_b_16(Bu, Bul, k0, NF, bn, bkh);
        __syncthreads();

        bf16x8 af[4], bgf[4], buf_[4];
        #pragma unroll
        for (int m = 0; m < 4; ++m)
            af[m] = *(const bf16x8*)&Al[(wm * 64 + m * 16 + lr) * BPAD + lq * 8];
        #pragma unroll
        for (int n = 0; n < 4; ++n) {
            bgf[n]  = *(const bf16x8*)&Bgl[(wn * 64 + n * 16 + lr) * BPAD + lq * 8];
            buf_[n] = *(const bf16x8*)&Bul[(wn * 64 + n * 16 + lr) * BPAD + lq * 8];
        }
        #pragma unroll
        for (int m = 0; m < 4; ++m)
            #pragma unroll
            for (int n = 0; n < 4; ++n) {
                accg[m][n] = __builtin_amdgcn_mfma_f32_16x16x32_bf16(af[m], bgf[n],  accg[m][n], 0, 0, 0);
                accu[m][n] = __builtin_amdgcn_mfma_f32_16x16x32_bf16(af[m], buf_[n], accu[m][n], 0, 0, 0);
            }
        __syncthreads();
    }

    #pragma unroll
    for (int m = 0; m < 4; ++m)
        #pragma unroll
        for (int n = 0; n < 4; ++n)
            #pragma unroll
            for (int r = 0; r < 4; ++r) {
                int row = wm * 64 + m * 16 + lq * 4 + r;
                int col = wn * 64 + n * 16 + lr;
                float g = accg[m][n][r], u = accu[m][n][r];
                float sg = g / (1.0f + expf(-g));   // silu
                out[(size_t)row * NF + col] = f2bf(sg * u);
            }
}

// ---------------------------------------------------------------------------
// GEMM2: eo[e] = hb[e] @ wd[e]    (M=CAP, N=NH, K=NF)
// tile 128x64x32, 256 threads (4 waves 2x2, wave = 64x32)
// ---------------------------------------------------------------------------
__global__ __launch_bounds__(256) void k_gemm2(
    const ushort* __restrict__ hb, const float* __restrict__ wd,
    float* __restrict__ eo)
{
    int e = blockIdx.z, mb = blockIdx.y, nb = blockIdx.x;
    const ushort* A = hb + (size_t)e * CAP * NF + (size_t)mb * 128 * NF;
    const float*  B = wd + (size_t)e * NF * NH + nb * 64;
    float* out = eo + (size_t)e * CAP * NH + (size_t)mb * 128 * NH + nb * 64;

    __shared__ __align__(16) ushort Al[128 * BPAD];
    __shared__ __align__(16) ushort Bl[64 * BPAD];

    int tid = threadIdx.x, lane = tid & 63, wid = tid >> 6;
    int wm = wid >> 1, wn = wid & 1;
    int lr = lane & 15, lq = lane >> 4;
    int bn = tid & 63;          // staging column
    int bg = tid >> 6;          // k-quarter (8 k each)

    f32x4 acc[4][2] = {};

    for (int k0 = 0; k0 < NF; k0 += 32) {
        #pragma unroll
        for (int i = 0; i < 2; ++i) {
            int L = tid + i * 256;
            int row = L >> 2, cg = (L & 3) * 8;
            uint4 av = *(const uint4*)(A + (size_t)row * NF + k0 + cg);
            *(uint4*)&Al[row * BPAD + cg] = av;
        }
        {
            union { ushort sh[8]; uint4 v; } p;
            #pragma unroll
            for (int j = 0; j < 8; ++j)
                p.sh[j] = f2bf(B[(k0 + bg * 8 + j) * NH + bn]);
            *(uint4*)&Bl[bn * BPAD + bg * 8] = p.v;
        }
        __syncthreads();

        bf16x8 af[4], bf_[2];
        #pragma unroll
        for (int m = 0; m < 4; ++m)
            af[m] = *(const bf16x8*)&Al[(wm * 64 + m * 16 + lr) * BPAD + lq * 8];
        #pragma unroll
        for (int n = 0; n < 2; ++n)
            bf_[n] = *(const bf16x8*)&Bl[(wn * 32 + n * 16 + lr) * BPAD + lq * 8];
        #pragma unroll
        for (int m = 0; m < 4; ++m)
            #pragma unroll
            for (int n = 0; n < 2; ++n)
                acc[m][n] = __builtin_amdgcn_mfma_f32_16x16x32_bf16(af[m], bf_[n], acc[m][n], 0, 0, 0);
        __syncthreads();
    }

    #pragma unroll
    for (int m = 0; m < 4; ++m)
        #pragma unroll
        for (int n = 0; n < 2; ++n)
            #pragma unroll
            for (int r = 0; r < 4; ++r) {
                int row = wm * 64 + m * 16 + lq * 4 + r;
                int col = wn * 32 + n * 16 + lr;
                out[(size_t)row * NH + col] = acc[m][n][r];
            }
}

// ---------------------------------------------------------------------------
// K5: out[t] = x[t] + w0*eo[e0][min(t,CAP-1)] + w1*eo[e1][min(t,CAP-1)]
// (reference gathers by CLAMPED TOKEN INDEX, not dispatch slot!)
// ---------------------------------------------------------------------------
__global__ __launch_bounds__(256) void k_final(
    const float* __restrict__ x, const float* __restrict__ eo,
    const int* __restrict__ idx, const float* __restrict__ wts,
    float* __restrict__ out)
{
    int t = blockIdx.x;
    int c = (t < CAP - 1) ? t : (CAP - 1);
    int e0 = idx[2*t], e1 = idx[2*t+1];
    float w0 = wts[2*t], w1 = wts[2*t+1];
    int h = threadIdx.x * 4;
    float4 xv = *(const float4*)(x + (size_t)t * NH + h);
    float4 a = *(const float4*)(eo + ((size_t)e0 * CAP + c) * NH + h);
    float4 b = *(const float4*)(eo + ((size_t)e1 * CAP + c) * NH + h);
    float4 o;
    o.x = xv.x + w0 * a.x + w1 * b.x;
    o.y = xv.y + w0 * a.y + w1 * b.y;
    o.z = xv.z + w0 * a.z + w1 * b.z;
    o.w = xv.w + w0 * a.w + w1 * b.w;
    *(float4*)(out + (size_t)t * NH + h) = o;
}

// ---------------------------------------------------------------------------
extern "C" void kernel_launch(void* const* d_in, const int* in_sizes, int n_in,
                              void* d_out, int out_size, void* d_ws, size_t ws_size,
                              hipStream_t stream)
{
    const float* x     = (const float*)d_in[0];
    const float* rw    = (const float*)d_in[1];
    const float* wg    = (const float*)d_in[2];
    const float* wu    = (const float*)d_in[3];
    const float* wd    = (const float*)d_in[4];
    const float* gamma = (const float*)d_in[5];
    const float* beta  = (const float*)d_in[6];
    float* out = (float*)d_out;

    char* ws = (char*)d_ws;
    ushort* tok_bf = (ushort*)(ws);                           // 8,388,608 B
    ushort* xin    = (ushort*)(ws + 8388608);                 // 10,485,760 B
    ushort* hb     = (ushort*)(ws + 18874368);                // 20,971,520 B
    float*  eo     = (float*) (ws + 39845888);                // 20,971,520 B
    int*    idx    = (int*)   (ws + 60817408);                // 32,768 B
    float*  wts    = (float*) (ws + 60850176);                // 32,768 B
    int*    sel    = (int*)   (ws + 60882944);                // 20,480 B
    // total ~58 MB of workspace

    k_ln_router<<<NT, 256, 0, stream>>>(x, rw, gamma, beta, tok_bf, idx, wts);
    k_build_sel<<<NE, 1024, 0, stream>>>(idx, sel);
    k_gather<<<NE * CAP, 256, 0, stream>>>(sel, tok_bf, xin);
    k_gemm1<<<dim3(NF / 128, CAP / 128, NE), 256, 0, stream>>>(xin, wg, wu, hb);
    k_gemm2<<<dim3(NH / 64, CAP / 128, NE), 256, 0, stream>>>(hb, wd, eo);
    k_final<<<NT, 256, 0, stream>>>(x, eo, idx, wts, out);
}

// Round 2
// 421.295 us; speedup vs baseline: 1.0438x; 1.0438x over previous
//
#include <hip/hip_runtime.h>
#include <hip/hip_bf16.h>

// Problem constants (from reference)
#define NE 8            // experts
#define NH 1024         // hidden
#define NF 2048         // ffn
#define NT 4096         // tokens = B*S
#define CAP 640         // ceil(1.25 * 4096 / 8)

typedef __bf16 bf16x8 __attribute__((ext_vector_type(8)));
typedef float f32x4 __attribute__((ext_vector_type(4)));

__device__ __forceinline__ ushort f2bf(float f) {
    union { float f; unsigned u; } v; v.f = f;
    unsigned r = (v.u + 0x7FFFu + ((v.u >> 16) & 1u)) >> 16;
    return (ushort)r;
}

// async global->LDS, 16B per lane, dest = wave-uniform base + lane*16
__device__ __forceinline__ void glds16(const ushort* g, ushort* l) {
    __builtin_amdgcn_global_load_lds((const __attribute__((address_space(1))) void*)g,
                                     (__attribute__((address_space(3))) void*)l,
                                     16, 0, 0);
}

// ---------------------------------------------------------------------------
// K0: transpose+convert  in fp32 [E][R][C]  ->  out bf16 [E][C][R]
// 64x64 tiles, 256 threads. Memory-bound; LDS conflicts irrelevant vs HBM rate.
// ---------------------------------------------------------------------------
__global__ __launch_bounds__(256) void k_transpose(
    const float* __restrict__ in, ushort* __restrict__ out, int R, int C)
{
    int e = blockIdx.z;
    int c0 = blockIdx.x * 64, r0 = blockIdx.y * 64;
    in  += (size_t)e * R * C;
    out += (size_t)e * R * C;

    __shared__ __align__(16) ushort lds[64 * 72];   // [c][r], stride 72 (144B, 16B-aligned)
    int t = threadIdx.x;
    int rl = t >> 4;            // 0..15
    int cl = (t & 15) * 4;      // 0..60

    #pragma unroll
    for (int i = 0; i < 4; ++i) {
        int r = i * 16 + rl;
        float4 v = *(const float4*)(in + (size_t)(r0 + r) * C + c0 + cl);
        lds[(cl + 0) * 72 + r] = f2bf(v.x);
        lds[(cl + 1) * 72 + r] = f2bf(v.y);
        lds[(cl + 2) * 72 + r] = f2bf(v.z);
        lds[(cl + 3) * 72 + r] = f2bf(v.w);
    }
    __syncthreads();

    int c = t >> 2, rq = (t & 3) * 16;
    uint4 a = *(const uint4*)&lds[c * 72 + rq];
    uint4 b = *(const uint4*)&lds[c * 72 + rq + 8];
    *(uint4*)(out + (size_t)(c0 + c) * R + r0 + rq)     = a;
    *(uint4*)(out + (size_t)(c0 + c) * R + r0 + rq + 8) = b;
}

// ---------------------------------------------------------------------------
// K1: per-token LayerNorm (fp32) + router logits + softmax + top-2
// ---------------------------------------------------------------------------
__global__ __launch_bounds__(256) void k_ln_router(
    const float* __restrict__ x, const float* __restrict__ rw,
    const float* __restrict__ gamma, const float* __restrict__ beta,
    ushort* __restrict__ tok_bf, int* __restrict__ idx, float* __restrict__ wts)
{
    int t = blockIdx.x, tid = threadIdx.x;
    int lane = tid & 63, wid = tid >> 6;
    const float* xp = x + (size_t)t * NH;

    float4 v = *(const float4*)(xp + tid * 4);
    float xs[4] = {v.x, v.y, v.z, v.w};
    float s = xs[0] + xs[1] + xs[2] + xs[3];
    float q = xs[0]*xs[0] + xs[1]*xs[1] + xs[2]*xs[2] + xs[3]*xs[3];

    __shared__ float rs[4], rq[4], rl[4][8];
    #pragma unroll
    for (int o = 32; o; o >>= 1) { s += __shfl_xor(s, o); q += __shfl_xor(q, o); }
    if (lane == 0) { rs[wid] = s; rq[wid] = q; }
    __syncthreads();
    float S = rs[0] + rs[1] + rs[2] + rs[3];
    float Q = rq[0] + rq[1] + rq[2] + rq[3];
    float mean = S * (1.0f / NH);
    float var  = Q * (1.0f / NH) - mean * mean;
    float rstd = 1.0f / sqrtf(var + 1e-5f);

    float le[8] = {0,0,0,0,0,0,0,0};
    ushort tb[4];
    #pragma unroll
    for (int j = 0; j < 4; ++j) {
        int h = tid * 4 + j;
        float nh = (xs[j] - mean) * rstd * gamma[h] + beta[h];
        tb[j] = f2bf(nh);
        float4 r0 = *(const float4*)(rw + h * 8);
        float4 r1 = *(const float4*)(rw + h * 8 + 4);
        le[0] += nh * r0.x; le[1] += nh * r0.y; le[2] += nh * r0.z; le[3] += nh * r0.w;
        le[4] += nh * r1.x; le[5] += nh * r1.y; le[6] += nh * r1.z; le[7] += nh * r1.w;
    }
    union { ushort s2[4]; uint2 u2; } pk;
    pk.s2[0]=tb[0]; pk.s2[1]=tb[1]; pk.s2[2]=tb[2]; pk.s2[3]=tb[3];
    *(uint2*)(tok_bf + (size_t)t * NH + tid * 4) = pk.u2;

    #pragma unroll
    for (int o = 32; o; o >>= 1)
        #pragma unroll
        for (int e = 0; e < 8; ++e) le[e] += __shfl_xor(le[e], o);
    if (lane == 0)
        #pragma unroll
        for (int e = 0; e < 8; ++e) rl[wid][e] = le[e];
    __syncthreads();

    if (tid == 0) {
        float l[8];
        #pragma unroll
        for (int e = 0; e < 8; ++e) l[e] = rl[0][e] + rl[1][e] + rl[2][e] + rl[3][e];
        float mx = l[0];
        #pragma unroll
        for (int e = 1; e < 8; ++e) mx = fmaxf(mx, l[e]);
        float p[8], den = 0.f;
        #pragma unroll
        for (int e = 0; e < 8; ++e) { p[e] = expf(l[e] - mx); den += p[e]; }
        float rden = 1.0f / den;
        #pragma unroll
        for (int e = 0; e < 8; ++e) p[e] *= rden;
        int i0 = 0; float b0 = p[0];
        #pragma unroll
        for (int e = 1; e < 8; ++e) if (p[e] > b0) { b0 = p[e]; i0 = e; }
        int i1 = (i0 == 0) ? 1 : 0; float b1 = p[i1];
        #pragma unroll
        for (int e = 0; e < 8; ++e) if (e != i0 && p[e] > b1) { b1 = p[e]; i1 = e; }
        float sw = 1.0f / (b0 + b1);
        idx[2*t] = i0; idx[2*t+1] = i1;
        wts[2*t] = b0 * sw; wts[2*t+1] = b1 * sw;
    }
}

// ---------------------------------------------------------------------------
// K2: per-expert ordered compaction (stable by token index, capacity CAP)
// ---------------------------------------------------------------------------
__global__ __launch_bounds__(1024) void k_build_sel(
    const int* __restrict__ idx, int* __restrict__ sel)
{
    int e = blockIdx.x, tid = threadIdx.x;
    int lane = tid & 63, wid = tid >> 6;
    __shared__ int wsum[16], wpre[16], sbase;
    if (tid < CAP) sel[e * CAP + tid] = -1;
    if (tid == 0) sbase = 0;
    __syncthreads();

    for (int ch = 0; ch < NT / 1024; ++ch) {
        int t = ch * 1024 + tid;
        int m = (idx[2*t] == e || idx[2*t+1] == e) ? 1 : 0;
        int v = m;
        #pragma unroll
        for (int d = 1; d < 64; d <<= 1) {
            int u = __shfl_up(v, d);
            if (lane >= d) v += u;
        }
        if (lane == 63) wsum[wid] = v;
        __syncthreads();
        if (tid < 16) {
            int ws = wsum[tid], wv = ws;
            #pragma unroll
            for (int d = 1; d < 16; d <<= 1) {
                int u = __shfl_up(wv, d);
                if (tid >= d) wv += u;
            }
            wpre[tid] = wv - ws;
        }
        __syncthreads();
        int base0 = sbase;
        int slot = base0 + wpre[wid] + v - m;
        if (m && slot < CAP) sel[e * CAP + slot] = t;
        __syncthreads();
        if (tid == 0) sbase = base0 + wpre[15] + wsum[15];
        __syncthreads();
    }
}

// ---------------------------------------------------------------------------
// K3: gather tokens into per-expert slot rows (zeros for invalid slots)
// ---------------------------------------------------------------------------
__global__ __launch_bounds__(256) void k_gather(
    const int* __restrict__ sel, const ushort* __restrict__ tok,
    ushort* __restrict__ xin)
{
    int sIdx = blockIdx.x;
    int tokid = sel[sIdx];
    uint2 v = make_uint2(0u, 0u);
    if (tokid >= 0)
        v = *(const uint2*)(tok + (size_t)tokid * NH + threadIdx.x * 4);
    *(uint2*)(xin + (size_t)sIdx * NH + threadIdx.x * 4) = v;
}

// ---------------------------------------------------------------------------
// GEMM1: hb[e] = silu(xin[e] @ wg[e]) * (xin[e] @ wu[e])  (M=CAP,N=NF,K=NH)
// m97 structure: 128x128 tile, BK=32, 4 waves 2x2, global_load_lds staging,
// linear LDS, bf16 MFMA 16x16x32, fused gate+up (shared A tile).
// Weights pre-transposed: wgT/wuT = [E][NF][NH] bf16 (K-contiguous rows).
// ---------------------------------------------------------------------------
__global__ __launch_bounds__(256) void k_gemm1(
    const ushort* __restrict__ xin, const ushort* __restrict__ wgT,
    const ushort* __restrict__ wuT, ushort* __restrict__ hb)
{
    int e = blockIdx.z, mb = blockIdx.y, nb = blockIdx.x;
    const ushort* A  = xin + (size_t)e * CAP * NH + (size_t)mb * 128 * NH;
    const ushort* Bg = wgT + (size_t)e * NF * NH + (size_t)nb * 128 * NH;
    const ushort* Bu = wuT + (size_t)e * NF * NH + (size_t)nb * 128 * NH;
    ushort* out = hb + (size_t)e * CAP * NF + (size_t)mb * 128 * NF + nb * 128;

    __shared__ __align__(16) ushort Al[128 * 32];
    __shared__ __align__(16) ushort Bgl[128 * 32];
    __shared__ __align__(16) ushort Bul[128 * 32];

    int tid = threadIdx.x, lane = tid & 63, wid = tid >> 6;
    int wm = wid >> 1, wn = wid & 1;
    int lr = lane & 15, lq = lane >> 4;
    int ldrow = lane >> 2;          // 0..15 within wave's 16-row slab
    int lcol  = (lane & 3) * 8;     // ushort offset within 64B row

    f32x4 accg[4][4] = {}; f32x4 accu[4][4] = {};

    for (int k0 = 0; k0 < NH; k0 += 32) {
        #pragma unroll
        for (int i = 0; i < 2; ++i) {
            int row = i * 64 + wid * 16 + ldrow;
            int lb  = i * 2048 + wid * 512;
            glds16(A  + (size_t)row * NH + k0 + lcol, Al  + lb);
            glds16(Bg + (size_t)row * NH + k0 + lcol, Bgl + lb);
            glds16(Bu + (size_t)row * NH + k0 + lcol, Bul + lb);
        }
        __syncthreads();

        bf16x8 af[4], bgf[4], buf_[4];
        #pragma unroll
        for (int m = 0; m < 4; ++m)
            af[m] = *(const bf16x8*)&Al[(wm * 64 + m * 16 + lr) * 32 + lq * 8];
        #pragma unroll
        for (int n = 0; n < 4; ++n) {
            bgf[n]  = *(const bf16x8*)&Bgl[(wn * 64 + n * 16 + lr) * 32 + lq * 8];
            buf_[n] = *(const bf16x8*)&Bul[(wn * 64 + n * 16 + lr) * 32 + lq * 8];
        }
        #pragma unroll
        for (int m = 0; m < 4; ++m)
            #pragma unroll
            for (int n = 0; n < 4; ++n) {
                accg[m][n] = __builtin_amdgcn_mfma_f32_16x16x32_bf16(af[m], bgf[n],  accg[m][n], 0, 0, 0);
                accu[m][n] = __builtin_amdgcn_mfma_f32_16x16x32_bf16(af[m], buf_[n], accu[m][n], 0, 0, 0);
            }
        __syncthreads();
    }

    #pragma unroll
    for (int m = 0; m < 4; ++m)
        #pragma unroll
        for (int n = 0; n < 4; ++n)
            #pragma unroll
            for (int r = 0; r < 4; ++r) {
                int row = wm * 64 + m * 16 + lq * 4 + r;
                int col = wn * 64 + n * 16 + lr;
                float g = accg[m][n][r], u = accu[m][n][r];
                float sg = g / (1.0f + expf(-g));
                out[(size_t)row * NF + col] = f2bf(sg * u);
            }
}

// ---------------------------------------------------------------------------
// GEMM2: eo[e] = hb[e] @ wd[e]   (M=CAP, N=NH, K=NF)
// 128x64 tile, BK=32, 4 waves 2x2 (wave 64x32), glds staging, wdT=[E][NH][NF].
// ---------------------------------------------------------------------------
__global__ __launch_bounds__(256) void k_gemm2(
    const ushort* __restrict__ hb, const ushort* __restrict__ wdT,
    float* __restrict__ eo)
{
    int e = blockIdx.z, mb = blockIdx.y, nb = blockIdx.x;
    const ushort* A = hb  + (size_t)e * CAP * NF + (size_t)mb * 128 * NF;
    const ushort* B = wdT + (size_t)e * NH * NF + (size_t)nb * 64 * NF;
    float* out = eo + (size_t)e * CAP * NH + (size_t)mb * 128 * NH + nb * 64;

    __shared__ __align__(16) ushort Al[128 * 32];
    __shared__ __align__(16) ushort Bl[64 * 32];

    int tid = threadIdx.x, lane = tid & 63, wid = tid >> 6;
    int wm = wid >> 1, wn = wid & 1;
    int lr = lane & 15, lq = lane >> 4;
    int ldrow = lane >> 2;
    int lcol  = (lane & 3) * 8;

    f32x4 acc[4][2] = {};

    for (int k0 = 0; k0 < NF; k0 += 32) {
        #pragma unroll
        for (int i = 0; i < 2; ++i) {
            int row = i * 64 + wid * 16 + ldrow;
            glds16(A + (size_t)row * NF + k0 + lcol, Al + i * 2048 + wid * 512);
        }
        glds16(B + (size_t)(wid * 16 + ldrow) * NF + k0 + lcol, Bl + wid * 512);
        __syncthreads();

        bf16x8 af[4], bf_[2];
        #pragma unroll
        for (int m = 0; m < 4; ++m)
            af[m] = *(const bf16x8*)&Al[(wm * 64 + m * 16 + lr) * 32 + lq * 8];
        #pragma unroll
        for (int n = 0; n < 2; ++n)
            bf_[n] = *(const bf16x8*)&Bl[(wn * 32 + n * 16 + lr) * 32 + lq * 8];
        #pragma unroll
        for (int m = 0; m < 4; ++m)
            #pragma unroll
            for (int n = 0; n < 2; ++n)
                acc[m][n] = __builtin_amdgcn_mfma_f32_16x16x32_bf16(af[m], bf_[n], acc[m][n], 0, 0, 0);
        __syncthreads();
    }

    #pragma unroll
    for (int m = 0; m < 4; ++m)
        #pragma unroll
        for (int n = 0; n < 2; ++n)
            #pragma unroll
            for (int r = 0; r < 4; ++r) {
                int row = wm * 64 + m * 16 + lq * 4 + r;
                int col = wn * 32 + n * 16 + lr;
                out[(size_t)row * NH + col] = acc[m][n][r];
            }
}

// ---------------------------------------------------------------------------
// K5: out[t] = x[t] + w0*eo[e0][min(t,CAP-1)] + w1*eo[e1][min(t,CAP-1)]
// ---------------------------------------------------------------------------
__global__ __launch_bounds__(256) void k_final(
    const float* __restrict__ x, const float* __restrict__ eo,
    const int* __restrict__ idx, const float* __restrict__ wts,
    float* __restrict__ out)
{
    int t = blockIdx.x;
    int c = (t < CAP - 1) ? t : (CAP - 1);
    int e0 = idx[2*t], e1 = idx[2*t+1];
    float w0 = wts[2*t], w1 = wts[2*t+1];
    int h = threadIdx.x * 4;
    float4 xv = *(const float4*)(x + (size_t)t * NH + h);
    float4 a = *(const float4*)(eo + ((size_t)e0 * CAP + c) * NH + h);
    float4 b = *(const float4*)(eo + ((size_t)e1 * CAP + c) * NH + h);
    float4 o;
    o.x = xv.x + w0 * a.x + w1 * b.x;
    o.y = xv.y + w0 * a.y + w1 * b.y;
    o.z = xv.z + w0 * a.z + w1 * b.z;
    o.w = xv.w + w0 * a.w + w1 * b.w;
    *(float4*)(out + (size_t)t * NH + h) = o;
}

// ---------------------------------------------------------------------------
extern "C" void kernel_launch(void* const* d_in, const int* in_sizes, int n_in,
                              void* d_out, int out_size, void* d_ws, size_t ws_size,
                              hipStream_t stream)
{
    const float* x     = (const float*)d_in[0];
    const float* rw    = (const float*)d_in[1];
    const float* wg    = (const float*)d_in[2];
    const float* wu    = (const float*)d_in[3];
    const float* wd    = (const float*)d_in[4];
    const float* gamma = (const float*)d_in[5];
    const float* beta  = (const float*)d_in[6];
    float* out = (float*)d_out;

    char* ws = (char*)d_ws;
    ushort* tok_bf = (ushort*)(ws);                 //  8,388,608 B
    ushort* xin    = (ushort*)(ws +   8388608);     // 10,485,760 B
    ushort* hb     = (ushort*)(ws +  18874368);     // 20,971,520 B
    float*  eo     = (float*) (ws +  39845888);     // 20,971,520 B
    ushort* wgT    = (ushort*)(ws +  60817408);     // 33,554,432 B
    ushort* wuT    = (ushort*)(ws +  94371840);     // 33,554,432 B
    ushort* wdT    = (ushort*)(ws + 127926272);     // 33,554,432 B
    int*    idx    = (int*)   (ws + 161480704);     //     32,768 B
    float*  wts    = (float*) (ws + 161513472);     //     32,768 B
    int*    sel    = (int*)   (ws + 161546240);     //     20,480 B
    // total ~161.6 MB

    // weight convert+transpose (one-shot, memory-bound)
    k_transpose<<<dim3(NF / 64, NH / 64, NE), 256, 0, stream>>>(wg, wgT, NH, NF);
    k_transpose<<<dim3(NF / 64, NH / 64, NE), 256, 0, stream>>>(wu, wuT, NH, NF);
    k_transpose<<<dim3(NH / 64, NF / 64, NE), 256, 0, stream>>>(wd, wdT, NF, NH);

    k_ln_router<<<NT, 256, 0, stream>>>(x, rw, gamma, beta, tok_bf, idx, wts);
    k_build_sel<<<NE, 1024, 0, stream>>>(idx, sel);
    k_gather<<<NE * CAP, 256, 0, stream>>>(sel, tok_bf, xin);
    k_gemm1<<<dim3(NF / 128, CAP / 128, NE), 256, 0, stream>>>(xin, wgT, wuT, hb);
    k_gemm2<<<dim3(NH / 64, CAP / 128, NE), 256, 0, stream>>>(hb, wdT, eo);
    k_final<<<NT, 256, 0, stream>>>(x, eo, idx, wts, out);
}